// Round 1
// baseline (2886.016 us; speedup 1.0000x reference)
//
#include <hip/hip_runtime.h>
#include <math.h>

// MFGN forward, MI355X. One block per outfit; all state in LDS.
// Phases: A creat_factors | B inter_factors (sequential scan) | C infer_items
//         D inter_items (sequential scan) | E score | F com_loss.

__device__ __forceinline__ float lrelu(float x) { return x > 0.0f ? x : 0.01f * x; }

__global__ void zero_com(float* out) { if (threadIdx.x == 0) out[2048] = 0.0f; }

__global__ __launch_bounds__(256, 2) void mfgn_kernel(
    const int* __restrict__ outfit_items,
    const float* __restrict__ items_feature,
    const int* __restrict__ items_neighbor,
    const float* __restrict__ cfW1, const float* __restrict__ cfb1,
    const float* __restrict__ cfW2, const float* __restrict__ cfb2,
    const float* __restrict__ f2fW1, const float* __restrict__ f2fb1,
    const float* __restrict__ f2fW2, const float* __restrict__ f2fb2,
    const float* __restrict__ f2iW1, const float* __restrict__ f2ib1,
    const float* __restrict__ f2iW2, const float* __restrict__ f2ib2,
    const float* __restrict__ i2iW1, const float* __restrict__ i2ib1,
    const float* __restrict__ i2iW2, const float* __restrict__ i2ib2,
    const float* __restrict__ o2sW, const float* __restrict__ o2sb,
    float* __restrict__ out)
{
  // fac stride 129 (pad) -> bank = (4*item + f + k) % 32 : <=2-way = free
  __shared__ float facL[16 * 516];    // [item][f][129]
  __shared__ float featL[16 * 129];   // [item][129]
  __shared__ float hT[128 * 64];      // transposed hidden: [col][row<=64]; phase A reuses as [4][64][17]
  __shared__ float scratch[8 * 132];  // B: add accum (512) | D: msg accum | E/F: reduction
  __shared__ int oiL[16];
  __shared__ int nbrL[16 * 8];
  __shared__ int clL[32];
  __shared__ int vslL[16];
  __shared__ int refcntL[16];
  __shared__ int ncL, nvsL;

  const int o = blockIdx.x;
  const int tid = (int)threadIdx.x;
  const int lane = tid & 63;
  const int wid = tid >> 6;
  const int c0 = __builtin_amdgcn_readfirstlane(wid * 32);  // wave's 32-col block

  // ---------------- load ----------------
  if (tid < 16) oiL[tid] = outfit_items[o * 16 + tid];
  for (int idx = tid; idx < 128; idx += 256) nbrL[idx] = items_neighbor[o * 128 + idx];
  for (int idx = tid; idx < 2048; idx += 256) {
    int n = idx >> 7, d = idx & 127;
    featL[n * 129 + d] = items_feature[o * 2048 + idx];
  }
  __syncthreads();
  if (tid == 0) {
    int cnt = 0;
    for (int s = 0; s < 16; ++s) refcntL[s] = 0;
    for (int s = 0; s < 16; ++s) {
      int v = oiL[s];
      if (v != -1) { vslL[cnt++] = s; refcntL[v]++; }
    }
    nvsL = cnt;
  }
  __syncthreads();
  const int nvs = nvsL;

  // ---------------- Phase A: creat_factors ----------------
  {
    float* hA = hT;  // [f][e][n] : f*1088 + e*17 + n
    const int n = tid & 15;
    const int eg = tid >> 4;  // 16 groups x 4 cols = 64 (D2)
    float acc1[16];
#pragma unroll
    for (int z = 0; z < 16; ++z) acc1[z] = 0.0f;
    for (int k = 0; k < 128; ++k) {
      float x = featL[n * 129 + k];
#pragma unroll
      for (int f = 0; f < 4; ++f) {
        const float4 wv = *(const float4*)(cfW1 + f * 8192 + k * 64 + eg * 4);
        acc1[f * 4 + 0] += x * wv.x; acc1[f * 4 + 1] += x * wv.y;
        acc1[f * 4 + 2] += x * wv.z; acc1[f * 4 + 3] += x * wv.w;
      }
    }
#pragma unroll
    for (int f = 0; f < 4; ++f)
#pragma unroll
      for (int j = 0; j < 4; ++j) {
        int e = eg * 4 + j;
        hA[f * 1088 + e * 17 + n] = lrelu(acc1[f * 4 + j] + cfb1[f * 64 + e]);
      }
    __syncthreads();
    // layer 2: thread -> (n, dg), dg covers 8 of 128 cols
    const int dg = tid >> 4;
    float acc2[32];
#pragma unroll
    for (int z = 0; z < 32; ++z) acc2[z] = 0.0f;
    for (int e = 0; e < 64; ++e) {
#pragma unroll
      for (int f = 0; f < 4; ++f) {
        float x = hA[f * 1088 + e * 17 + n];
        const float4 wa = *(const float4*)(cfW2 + f * 8192 + e * 128 + dg * 8);
        const float4 wb = *(const float4*)(cfW2 + f * 8192 + e * 128 + dg * 8 + 4);
        acc2[f * 8 + 0] += x * wa.x; acc2[f * 8 + 1] += x * wa.y;
        acc2[f * 8 + 2] += x * wa.z; acc2[f * 8 + 3] += x * wa.w;
        acc2[f * 8 + 4] += x * wb.x; acc2[f * 8 + 5] += x * wb.y;
        acc2[f * 8 + 6] += x * wb.z; acc2[f * 8 + 7] += x * wb.w;
      }
    }
#pragma unroll
    for (int f = 0; f < 4; ++f)
#pragma unroll
      for (int j = 0; j < 8; ++j) {
        int d = dg * 8 + j;
        facL[n * 516 + f * 129 + d] = lrelu(acc2[f * 8 + j] + cfb2[f * 128 + d]);
      }
    __syncthreads();
  }

  // ---------------- Phase B: inter_factors (sequential over slots) ----------------
  for (int s = 0; s < 16; ++s) {
    const int iv = oiL[s];
    if (iv == -1) continue;
    for (int idx = tid; idx < 512; idx += 256) scratch[idx] = 0.0f;
    if (tid < 64) {  // wave 0 builds compacted candidate list
      int cand = -1;
      if (tid < 24) cand = (tid < 16) ? oiL[tid] : nbrL[iv * 8 + (tid - 16)];
      bool ok = (tid < 24) && (cand != -1) && (cand != iv);
      unsigned long long bm = __ballot(ok);
      if (ok) clL[__popcll(bm & ((1ull << tid) - 1ull))] = cand;
      if (tid == 0) ncL = (int)__popcll(bm);
    }
    __syncthreads();
    const int rows = ncL * 4;
    if (rows > 0) {
      for (int base = 0; base < rows; base += 64) {
        const int myrow = base + lane;
        const bool active = myrow < rows;
        const int f = myrow & 3;
        const int citem = active ? clL[myrow >> 2] : 0;
        const int tOff = iv * 516 + f * 129;
        const int cOff = citem * 516 + f * 129;
        float acc[32];
#pragma unroll
        for (int z = 0; z < 32; ++z) acc[z] = 0.0f;
#pragma unroll 2
        for (int k = 0; k < 128; ++k) {
          float x = facL[tOff + k] * facL[cOff + k];  // t[f,k] * fac[cand,f,k]
          const float* wr = f2fW1 + k * 128 + c0;
#pragma unroll
          for (int cq = 0; cq < 8; ++cq) {
            const float4 wv = *(const float4*)(wr + cq * 4);
            acc[cq * 4 + 0] += x * wv.x; acc[cq * 4 + 1] += x * wv.y;
            acc[cq * 4 + 2] += x * wv.z; acc[cq * 4 + 3] += x * wv.w;
          }
        }
#pragma unroll
        for (int c = 0; c < 32; ++c)
          hT[(c0 + c) * 64 + lane] = lrelu(acc[c] + f2fb1[c0 + c]);
        __syncthreads();
#pragma unroll
        for (int z = 0; z < 32; ++z) acc[z] = 0.0f;
#pragma unroll 2
        for (int k = 0; k < 128; ++k) {
          float x = hT[k * 64 + lane];
          const float* wr = f2fW2 + k * 128 + c0;
#pragma unroll
          for (int cq = 0; cq < 8; ++cq) {
            const float4 wv = *(const float4*)(wr + cq * 4);
            acc[cq * 4 + 0] += x * wv.x; acc[cq * 4 + 1] += x * wv.y;
            acc[cq * 4 + 2] += x * wv.z; acc[cq * 4 + 3] += x * wv.w;
          }
        }
#pragma unroll
        for (int c = 0; c < 32; ++c) {
          float y = lrelu(acc[c] + f2fb2[c0 + c]);
          y = active ? y : 0.0f;
          y += __shfl_xor(y, 4);   // reduce over candidate bits (rows are c*4+f)
          y += __shfl_xor(y, 8);
          y += __shfl_xor(y, 16);
          y += __shfl_xor(y, 32);
          acc[c] = y;
        }
        if (lane < 4) {  // lane == f
#pragma unroll
          for (int c = 0; c < 32; ++c) scratch[lane * 128 + c0 + c] += acc[c];
        }
        __syncthreads();
      }
      for (int idx = tid; idx < 512; idx += 256) {
        int f = idx >> 7, d = idx & 127;
        facL[iv * 516 + f * 129 + d] += scratch[idx];
      }
    }
    __syncthreads();
  }

  // ---------------- Phase C: infer_items ----------------
  {
    const int n = lane >> 2, f = lane & 3;  // 64 rows = (item, factor)
    const int xOff = n * 516 + f * 129;
    float acc[32];
#pragma unroll
    for (int z = 0; z < 32; ++z) acc[z] = 0.0f;
#pragma unroll 2
    for (int k = 0; k < 128; ++k) {
      float x = facL[xOff + k];
      const float* wr = f2iW1 + k * 128 + c0;
#pragma unroll
      for (int cq = 0; cq < 8; ++cq) {
        const float4 wv = *(const float4*)(wr + cq * 4);
        acc[cq * 4 + 0] += x * wv.x; acc[cq * 4 + 1] += x * wv.y;
        acc[cq * 4 + 2] += x * wv.z; acc[cq * 4 + 3] += x * wv.w;
      }
    }
#pragma unroll
    for (int c = 0; c < 32; ++c)
      hT[(c0 + c) * 64 + lane] = lrelu(acc[c] + f2ib1[c0 + c]);
    __syncthreads();
#pragma unroll
    for (int z = 0; z < 32; ++z) acc[z] = 0.0f;
#pragma unroll 2
    for (int k = 0; k < 128; ++k) {
      float x = hT[k * 64 + lane];
      const float* wr = f2iW2 + k * 128 + c0;
#pragma unroll
      for (int cq = 0; cq < 8; ++cq) {
        const float4 wv = *(const float4*)(wr + cq * 4);
        acc[cq * 4 + 0] += x * wv.x; acc[cq * 4 + 1] += x * wv.y;
        acc[cq * 4 + 2] += x * wv.z; acc[cq * 4 + 3] += x * wv.w;
      }
    }
#pragma unroll
    for (int c = 0; c < 32; ++c) {
      float y = lrelu(acc[c] + f2ib2[c0 + c]);
      y += __shfl_xor(y, 1);  // sum over factors
      y += __shfl_xor(y, 2);
      if ((lane & 3) == 0)
        featL[n * 129 + c0 + c] += (float)refcntL[n] * y;
    }
    __syncthreads();
  }

  // ---------------- Phase D: inter_items (sequential over valid slots) ----------------
  for (int u = 0; u < nvs; ++u) {
    const int iv = oiL[vslL[u]];
    for (int idx = tid; idx < 1056; idx += 256) scratch[idx] = 0.0f;
    __syncthreads();
    for (int sb = 0; sb < nvs; sb += 8) {
      const int q = lane >> 3;   // 8 k-groups of 16
      const int sjl = lane & 7;  // slot-list index within chunk
      const int sj = sb + sjl;
      const bool act = sj < nvs;
      const int jitem = act ? oiL[vslL[sj]] : 0;
      const bool mm = act && (jitem != iv);
      float acc[32];
#pragma unroll
      for (int z = 0; z < 32; ++z) acc[z] = 0.0f;
      for (int kk = 0; kk < 16; ++kk) {
        const int k = q * 16 + kk;
        float x = featL[jitem * 129 + k];
        const float* wr = i2iW1 + k * 128 + c0;
#pragma unroll
        for (int cq = 0; cq < 8; ++cq) {
          const float4 wv = *(const float4*)(wr + cq * 4);
          acc[cq * 4 + 0] += x * wv.x; acc[cq * 4 + 1] += x * wv.y;
          acc[cq * 4 + 2] += x * wv.z; acc[cq * 4 + 3] += x * wv.w;
        }
      }
#pragma unroll
      for (int c = 0; c < 32; ++c) {
        float v = acc[c];
        v += __shfl_xor(v, 8); v += __shfl_xor(v, 16); v += __shfl_xor(v, 32);
        acc[c] = v;
      }
      if (q == 0) {
#pragma unroll
        for (int c = 0; c < 32; ++c)
          hT[(c0 + c) * 64 + sjl] = lrelu(acc[c] + i2ib1[c0 + c]);
      }
      __syncthreads();
#pragma unroll
      for (int z = 0; z < 32; ++z) acc[z] = 0.0f;
      for (int kk = 0; kk < 16; ++kk) {
        const int k = q * 16 + kk;
        float x = hT[k * 64 + sjl];
        const float* wr = i2iW2 + k * 128 + c0;
#pragma unroll
        for (int cq = 0; cq < 8; ++cq) {
          const float4 wv = *(const float4*)(wr + cq * 4);
          acc[cq * 4 + 0] += x * wv.x; acc[cq * 4 + 1] += x * wv.y;
          acc[cq * 4 + 2] += x * wv.z; acc[cq * 4 + 3] += x * wv.w;
        }
      }
#pragma unroll
      for (int c = 0; c < 32; ++c) {
        float v = acc[c];
        v += __shfl_xor(v, 8); v += __shfl_xor(v, 16); v += __shfl_xor(v, 32);
        acc[c] = v;
      }
      if (q == 0 && mm) {
#pragma unroll
        for (int c = 0; c < 32; ++c)
          scratch[sjl * 132 + c0 + c] += lrelu(acc[c] + i2ib2[c0 + c]);
      }
      __syncthreads();
    }
    if (tid < 128) {
      float sum = featL[iv * 129 + tid];
#pragma unroll
      for (int r = 0; r < 8; ++r) sum += scratch[r * 132 + tid];
      featL[iv * 129 + tid] = sum;
    }
    __syncthreads();
  }

  // ---------------- Phase E: infer_outfit + score ----------------
  if (tid < 128) {
    float sum = 0.0f;
    for (int u = 0; u < nvs; ++u) sum += featL[oiL[vslL[u]] * 129 + tid];
    float v = sum * o2sW[tid];
#pragma unroll
    for (int off = 1; off < 64; off <<= 1) v += __shfl_xor(v, off);
    if (lane == 0) scratch[wid] = v;
  }
  __syncthreads();
  if (tid == 0) {
    float t = scratch[0] + scratch[1] + o2sb[0];
    out[o] = 1.0f / (1.0f + expf(-t));
  }
  __syncthreads();

  // ---------------- Phase F: com_loss ----------------
  {
    const int n = tid >> 4, f = (tid >> 2) & 3, g = tid & 3;
    const int aOff = n * 516 + f * 129, bOff = n * 516 + g * 129;
    float dot = 0.0f;
    for (int k = 0; k < 128; ++k) dot += facL[aOff + k] * facL[bOff + k];
    float v = dot - ((f == g) ? 1.0f : 0.0f);
    float sq = (oiL[n] != -1) ? v * v : 0.0f;  // positional slot mask on item n
#pragma unroll
    for (int off = 1; off < 64; off <<= 1) sq += __shfl_xor(sq, off);
    if (lane == 0) scratch[wid] = sq;
    __syncthreads();
    if (tid == 0) {
      float tot = scratch[0] + scratch[1] + scratch[2] + scratch[3];
      atomicAdd(out + 2048, tot * (1.0f / 2048.0f));
    }
  }
}

extern "C" void kernel_launch(void* const* d_in, const int* in_sizes, int n_in,
                              void* d_out, int out_size, void* d_ws, size_t ws_size,
                              hipStream_t stream) {
  float* out = (float*)d_out;
  hipLaunchKernelGGL(zero_com, dim3(1), dim3(64), 0, stream, out);
  hipLaunchKernelGGL(mfgn_kernel, dim3(2048), dim3(256), 0, stream,
                     (const int*)d_in[0],
                     (const float*)d_in[1],
                     (const int*)d_in[2],
                     // d_in[3] items_factors unused (overwritten by creat_factors)
                     (const float*)d_in[4], (const float*)d_in[5],
                     (const float*)d_in[6], (const float*)d_in[7],
                     (const float*)d_in[8], (const float*)d_in[9],
                     (const float*)d_in[10], (const float*)d_in[11],
                     (const float*)d_in[12], (const float*)d_in[13],
                     (const float*)d_in[14], (const float*)d_in[15],
                     (const float*)d_in[16], (const float*)d_in[17],
                     (const float*)d_in[18], (const float*)d_in[19],
                     (const float*)d_in[20], (const float*)d_in[21],
                     out);
}

// Round 2
// 393.696 us; speedup vs baseline: 7.3306x; 7.3306x over previous
//
#include <hip/hip_runtime.h>
#include <math.h>

// MFGN forward, MI355X — MFMA (bf16 in / fp32 acc) version.
// One block per outfit; fp32 state (facL, featL) in LDS; bf16 staging buffer AB
// shared between MFMA A-operand (Xa) and hidden (hid) via barriers.
// MFMA 16x16x32 bf16 layouts (learn_hip-verified):
//   A: lane holds A[m=lane&15][k=(lane>>4)*8 + j], j=0..7 (contiguous k)
//   B: lane holds B[k=(lane>>4)*8 + j][n=lane&15]
//   C/D: col=lane&15, row=(lane>>4)*4 + reg

typedef __attribute__((ext_vector_type(8))) short short8;
typedef __attribute__((ext_vector_type(4))) float f32x4;

#define MFMA16(a, b, c) __builtin_amdgcn_mfma_f32_16x16x32_bf16(a, b, c, 0, 0, 0)

__device__ __forceinline__ float lrelu(float x) { return x > 0.0f ? x : 0.01f * x; }

__device__ __forceinline__ ushort f2bf(float f) {
  unsigned u = __builtin_bit_cast(unsigned, f);
  u += 0x7fffu + ((u >> 16) & 1u);  // RNE (finite inputs)
  return (ushort)(u >> 16);
}

// Gather a B-fragment from row-major fp32 W[k][ldn]: s[j] = bf16(W[kbase+j][col])
__device__ __forceinline__ short8 load_bfrag(const float* __restrict__ W, int ldn,
                                             int kbase, int col) {
  short8 r;
#pragma unroll
  for (int j = 0; j < 8; ++j) r[j] = (short)f2bf(W[(kbase + j) * ldn + col]);
  return r;
}

__global__ void zero_com(float* out) { if (threadIdx.x == 0) out[2048] = 0.0f; }

__global__ __launch_bounds__(256, 2) void mfgn_kernel(
    const int* __restrict__ outfit_items,
    const float* __restrict__ items_feature,
    const int* __restrict__ items_neighbor,
    const float* __restrict__ cfW1, const float* __restrict__ cfb1,
    const float* __restrict__ cfW2, const float* __restrict__ cfb2,
    const float* __restrict__ f2fW1, const float* __restrict__ f2fb1,
    const float* __restrict__ f2fW2, const float* __restrict__ f2fb2,
    const float* __restrict__ f2iW1, const float* __restrict__ f2ib1,
    const float* __restrict__ f2iW2, const float* __restrict__ f2ib2,
    const float* __restrict__ i2iW1, const float* __restrict__ i2ib1,
    const float* __restrict__ i2iW2, const float* __restrict__ i2ib2,
    const float* __restrict__ o2sW, const float* __restrict__ o2sb,
    float* __restrict__ out)
{
  // facL: [item][f][132] fp32, item stride 528 dw (rows 16B-aligned, bank shift 4)
  __shared__ float facL[16 * 528];                               // 33792 B
  __shared__ float featL[16 * 132];                              // 8448 B
  __shared__ ushort AB[64 * 136] __attribute__((aligned(16)));   // 17408 B, row stride 272 B
  __shared__ float msgs[8 * 132];                                // 4224 B
  __shared__ float redE[16];
  __shared__ int oiL[16];
  __shared__ int nbrL[128];
  __shared__ int clAll[16 * 16];
  __shared__ int ncAll[16];
  __shared__ int vslL[16];
  __shared__ int refcntL[16];
  __shared__ int nvsL;

  const int o = blockIdx.x;
  const int tid = (int)threadIdx.x;
  const int lane = tid & 63;
  const int wid = tid >> 6;
  const int n16 = lane & 15;   // col-in-tile / row-in-tile
  const int q = lane >> 4;     // quad
  const int kb = q * 8;        // k offset inside a 32-k tile

  // ---------------- load inputs ----------------
  if (tid < 16) oiL[tid] = outfit_items[o * 16 + tid];
  if (tid < 128) nbrL[tid] = items_neighbor[o * 128 + tid];
  {
    const int n = tid >> 4, d0 = (tid & 15) * 8;
    float4 a = *(const float4*)(items_feature + o * 2048 + tid * 8);
    float4 b = *(const float4*)(items_feature + o * 2048 + tid * 8 + 4);
    *(float4*)(featL + n * 132 + d0) = a;
    *(float4*)(featL + n * 132 + d0 + 4) = b;
    short8 pk;
    pk[0] = (short)f2bf(a.x); pk[1] = (short)f2bf(a.y);
    pk[2] = (short)f2bf(a.z); pk[3] = (short)f2bf(a.w);
    pk[4] = (short)f2bf(b.x); pk[5] = (short)f2bf(b.y);
    pk[6] = (short)f2bf(b.z); pk[7] = (short)f2bf(b.w);
    *(short8*)(AB + n * 136 + d0) = pk;  // featB rows 0..15
  }
  __syncthreads();

  // valid-slot list, refcounts (thread 0); candidate lists (one wave per slot group)
  if (tid == 0) {
    int cnt = 0;
    for (int s = 0; s < 16; ++s) refcntL[s] = 0;
    for (int s = 0; s < 16; ++s) {
      int v = oiL[s];
      if (v != -1) { vslL[cnt++] = s; refcntL[v]++; }
    }
    nvsL = cnt;
  }
  for (int s = wid; s < 16; s += 4) {
    const int iv = oiL[s];
    if (iv == -1) { if (lane == 0) ncAll[s] = 0; continue; }
    int cand = -1;
    if (lane < 24) cand = (lane < 16) ? oiL[lane] : nbrL[iv * 8 + (lane - 16)];
    bool ok = (lane < 24) && (cand != -1) && (cand != iv);
    unsigned long long bm = __ballot(ok);
    if (ok) clAll[s * 16 + __popcll(bm & ((1ull << lane) - 1ull))] = cand;
    if (lane == 0) ncAll[s] = (int)__popcll(bm);
  }
  __syncthreads();
  const int nvs = nvsL;

  // ---------------- Phase A: creat_factors (wave = factor) ----------------
  {
    const int f = wid;
    // layer 1: [16x128] @ W1[f][128x64]
    f32x4 acc1[4];
#pragma unroll
    for (int nt = 0; nt < 4; ++nt) acc1[nt] = (f32x4){0.f, 0.f, 0.f, 0.f};
    for (int kt = 0; kt < 4; ++kt) {
      short8 a = *(const short8*)(AB + n16 * 136 + kt * 32 + kb);
#pragma unroll
      for (int nt = 0; nt < 4; ++nt) {
        short8 b = load_bfrag(cfW1 + f * 8192, 64, kt * 32 + kb, nt * 16 + n16);
        acc1[nt] = MFMA16(a, b, acc1[nt]);
      }
    }
    ushort* hidA = AB + 2176 + f * 1152;  // [16 items][72 e] per factor (wave-private)
#pragma unroll
    for (int nt = 0; nt < 4; ++nt)
#pragma unroll
      for (int r = 0; r < 4; ++r) {
        int item = q * 4 + r, e = nt * 16 + n16;
        hidA[item * 72 + e] = f2bf(lrelu(acc1[nt][r] + cfb1[f * 64 + e]));
      }
    // layer 2: [16x64] @ W2[f][64x128] (same-wave LDS dependency; hw waits suffice)
    f32x4 acc2[8];
#pragma unroll
    for (int nt = 0; nt < 8; ++nt) acc2[nt] = (f32x4){0.f, 0.f, 0.f, 0.f};
    for (int kt = 0; kt < 2; ++kt) {
      short8 a = *(const short8*)(hidA + n16 * 72 + kt * 32 + kb);
#pragma unroll
      for (int nt = 0; nt < 8; ++nt) {
        short8 b = load_bfrag(cfW2 + f * 8192, 128, kt * 32 + kb, nt * 16 + n16);
        acc2[nt] = MFMA16(a, b, acc2[nt]);
      }
    }
#pragma unroll
    for (int nt = 0; nt < 8; ++nt)
#pragma unroll
      for (int r = 0; r < 4; ++r) {
        int item = q * 4 + r, d = nt * 16 + n16;
        facL[item * 528 + f * 132 + d] = lrelu(acc2[nt][r] + cfb2[f * 128 + d]);
      }
  }
  __syncthreads();

  // ---------------- Phase B: inter_factors ----------------
  {
    const int ntg0 = wid * 2;               // wave's two 16-col tiles
    const int col0 = ntg0 * 16 + n16, col1 = col0 + 16;
    short8 w1f[2][4], w2f[2][4];
#pragma unroll
    for (int ntl = 0; ntl < 2; ++ntl)
#pragma unroll
      for (int kt = 0; kt < 4; ++kt) {
        w1f[ntl][kt] = load_bfrag(f2fW1, 128, kt * 32 + kb, (ntg0 + ntl) * 16 + n16);
        w2f[ntl][kt] = load_bfrag(f2fW2, 128, kt * 32 + kb, (ntg0 + ntl) * 16 + n16);
      }
    const float b1v0 = f2fb1[col0], b1v1 = f2fb1[col1];
    const float b2v0 = f2fb2[col0], b2v1 = f2fb2[col1];

    for (int s = 0; s < 16; ++s) {
      const int iv = oiL[s];
      if (iv == -1) continue;
      const int nc = ncAll[s];
      // stage Xa[r][k] = bf16(fac[iv][f][k] * fac[cand][f][k]), r = ci*4+f
      {
        const int r = tid >> 2, kc = tid & 3;
        const int f = r & 3, ci = r >> 2;
        ushort* dst = AB + r * 136 + kc * 32;
        if (ci < nc) {
          const int cit = clAll[s * 16 + ci];
          const float* tp = facL + iv * 528 + f * 132 + kc * 32;
          const float* cp = facL + cit * 528 + f * 132 + kc * 32;
#pragma unroll
          for (int i = 0; i < 8; ++i) {
            float4 tv = *(const float4*)(tp + i * 4);
            float4 cv = *(const float4*)(cp + i * 4);
            ushort4 pk;
            pk.x = f2bf(tv.x * cv.x); pk.y = f2bf(tv.y * cv.y);
            pk.z = f2bf(tv.z * cv.z); pk.w = f2bf(tv.w * cv.w);
            *(ushort4*)(dst + i * 4) = pk;
          }
        } else {
          ushort4 z; z.x = z.y = z.z = z.w = 0;
#pragma unroll
          for (int i = 0; i < 8; ++i) *(ushort4*)(dst + i * 4) = z;
        }
      }
      __syncthreads();
      // layer 1
      f32x4 acc[4][2];
#pragma unroll
      for (int mt = 0; mt < 4; ++mt) { acc[mt][0] = (f32x4){0.f,0.f,0.f,0.f}; acc[mt][1] = (f32x4){0.f,0.f,0.f,0.f}; }
      for (int kt = 0; kt < 4; ++kt)
#pragma unroll
        for (int mt = 0; mt < 4; ++mt) {
          short8 a = *(const short8*)(AB + (mt * 16 + n16) * 136 + kt * 32 + kb);
          acc[mt][0] = MFMA16(a, w1f[0][kt], acc[mt][0]);
          acc[mt][1] = MFMA16(a, w1f[1][kt], acc[mt][1]);
        }
      __syncthreads();  // everyone done reading Xa
#pragma unroll
      for (int mt = 0; mt < 4; ++mt)
#pragma unroll
        for (int r = 0; r < 4; ++r) {
          int row = mt * 16 + q * 4 + r;
          AB[row * 136 + col0] = f2bf(lrelu(acc[mt][0][r] + b1v0));
          AB[row * 136 + col1] = f2bf(lrelu(acc[mt][1][r] + b1v1));
        }
      __syncthreads();
      // layer 2
#pragma unroll
      for (int mt = 0; mt < 4; ++mt) { acc[mt][0] = (f32x4){0.f,0.f,0.f,0.f}; acc[mt][1] = (f32x4){0.f,0.f,0.f,0.f}; }
      for (int kt = 0; kt < 4; ++kt)
#pragma unroll
        for (int mt = 0; mt < 4; ++mt) {
          short8 a = *(const short8*)(AB + (mt * 16 + n16) * 136 + kt * 32 + kb);
          acc[mt][0] = MFMA16(a, w2f[0][kt], acc[mt][0]);
          acc[mt][1] = MFMA16(a, w2f[1][kt], acc[mt][1]);
        }
      // epilogue: y=lrelu(acc+b2), mask rows (clidx = mt*4+q < nc), sum rows per f=reg
      float part[2][4];
#pragma unroll
      for (int ntl = 0; ntl < 2; ++ntl)
#pragma unroll
        for (int r = 0; r < 4; ++r) part[ntl][r] = 0.0f;
#pragma unroll
      for (int mt = 0; mt < 4; ++mt) {
        bool act = (mt * 4 + q) < nc;
#pragma unroll
        for (int r = 0; r < 4; ++r) {
          float y0 = lrelu(acc[mt][0][r] + b2v0);
          float y1 = lrelu(acc[mt][1][r] + b2v1);
          if (act) { part[0][r] += y0; part[1][r] += y1; }
        }
      }
#pragma unroll
      for (int ntl = 0; ntl < 2; ++ntl)
#pragma unroll
        for (int r = 0; r < 4; ++r) {
          float v = part[ntl][r];
          v += __shfl_xor(v, 16);
          v += __shfl_xor(v, 32);
          part[ntl][r] = v;
        }
      if (q == 0) {
#pragma unroll
        for (int r = 0; r < 4; ++r) {
          facL[iv * 528 + r * 132 + col0] += part[0][r];
          facL[iv * 528 + r * 132 + col1] += part[1][r];
        }
      }
      __syncthreads();
    }
  }

  // ---------------- Phase C: infer_items ----------------
  {
    const int ntg0 = wid * 2;
    const int col0 = ntg0 * 16 + n16, col1 = col0 + 16;
    short8 w1f[2][4], w2f[2][4];
#pragma unroll
    for (int ntl = 0; ntl < 2; ++ntl)
#pragma unroll
      for (int kt = 0; kt < 4; ++kt) {
        w1f[ntl][kt] = load_bfrag(f2iW1, 128, kt * 32 + kb, (ntg0 + ntl) * 16 + n16);
        w2f[ntl][kt] = load_bfrag(f2iW2, 128, kt * 32 + kb, (ntg0 + ntl) * 16 + n16);
      }
    const float b1v0 = f2ib1[col0], b1v1 = f2ib1[col1];
    const float b2v0 = f2ib2[col0], b2v1 = f2ib2[col1];
    // stage Xa[r=n*4+f][k] = bf16(fac[n][f][k])
    {
      const int r = tid >> 2, kc = tid & 3;
      const int f = r & 3, n = r >> 2;
      const float* sp = facL + n * 528 + f * 132 + kc * 32;
      ushort* dst = AB + r * 136 + kc * 32;
#pragma unroll
      for (int i = 0; i < 8; ++i) {
        float4 v = *(const float4*)(sp + i * 4);
        ushort4 pk;
        pk.x = f2bf(v.x); pk.y = f2bf(v.y); pk.z = f2bf(v.z); pk.w = f2bf(v.w);
        *(ushort4*)(dst + i * 4) = pk;
      }
    }
    __syncthreads();
    f32x4 acc[4][2];
#pragma unroll
    for (int mt = 0; mt < 4; ++mt) { acc[mt][0] = (f32x4){0.f,0.f,0.f,0.f}; acc[mt][1] = (f32x4){0.f,0.f,0.f,0.f}; }
    for (int kt = 0; kt < 4; ++kt)
#pragma unroll
      for (int mt = 0; mt < 4; ++mt) {
        short8 a = *(const short8*)(AB + (mt * 16 + n16) * 136 + kt * 32 + kb);
        acc[mt][0] = MFMA16(a, w1f[0][kt], acc[mt][0]);
        acc[mt][1] = MFMA16(a, w1f[1][kt], acc[mt][1]);
      }
    __syncthreads();
#pragma unroll
    for (int mt = 0; mt < 4; ++mt)
#pragma unroll
      for (int r = 0; r < 4; ++r) {
        int row = mt * 16 + q * 4 + r;
        AB[row * 136 + col0] = f2bf(lrelu(acc[mt][0][r] + b1v0));
        AB[row * 136 + col1] = f2bf(lrelu(acc[mt][1][r] + b1v1));
      }
    __syncthreads();
#pragma unroll
    for (int mt = 0; mt < 4; ++mt) { acc[mt][0] = (f32x4){0.f,0.f,0.f,0.f}; acc[mt][1] = (f32x4){0.f,0.f,0.f,0.f}; }
    for (int kt = 0; kt < 4; ++kt)
#pragma unroll
      for (int mt = 0; mt < 4; ++mt) {
        short8 a = *(const short8*)(AB + (mt * 16 + n16) * 136 + kt * 32 + kb);
        acc[mt][0] = MFMA16(a, w2f[0][kt], acc[mt][0]);
        acc[mt][1] = MFMA16(a, w2f[1][kt], acc[mt][1]);
      }
    // g[item][col] = sum_f y; feat[item] += refcnt[item]*g  (item = mt*4+q)
#pragma unroll
    for (int mt = 0; mt < 4; ++mt) {
      int item = mt * 4 + q;
      float g0 = 0.f, g1 = 0.f;
#pragma unroll
      for (int r = 0; r < 4; ++r) {
        g0 += lrelu(acc[mt][0][r] + b2v0);
        g1 += lrelu(acc[mt][1][r] + b2v1);
      }
      float rc = (float)refcntL[item];
      featL[item * 132 + col0] += rc * g0;
      featL[item * 132 + col1] += rc * g1;
    }
    __syncthreads();
  }

  // ---------------- Phase D: inter_items (sequential over valid slots) ----------------
  {
    const int ntg0 = wid * 2;
    const int col0 = ntg0 * 16 + n16, col1 = col0 + 16;
    short8 w1f[2][4], w2f[2][4];
#pragma unroll
    for (int ntl = 0; ntl < 2; ++ntl)
#pragma unroll
      for (int kt = 0; kt < 4; ++kt) {
        w1f[ntl][kt] = load_bfrag(i2iW1, 128, kt * 32 + kb, (ntg0 + ntl) * 16 + n16);
        w2f[ntl][kt] = load_bfrag(i2iW2, 128, kt * 32 + kb, (ntg0 + ntl) * 16 + n16);
      }
    const float b1v0 = i2ib1[col0], b1v1 = i2ib1[col1];
    const float b2v0 = i2ib2[col0], b2v1 = i2ib2[col1];

    for (int u = 0; u < nvs; ++u) {
      const int iv = oiL[vslL[u]];
      // stage Xa rows j<nvs from current feat
      {
        const int j = tid >> 5, kq = (tid & 31) * 4;
        if (j < nvs) {
          const int it = oiL[vslL[j]];
          float4 v = *(const float4*)(featL + it * 132 + kq);
          ushort4 pk;
          pk.x = f2bf(v.x); pk.y = f2bf(v.y); pk.z = f2bf(v.z); pk.w = f2bf(v.w);
          *(ushort4*)(AB + j * 136 + kq) = pk;
        }
      }
      __syncthreads();
      f32x4 acc[2];
      acc[0] = (f32x4){0.f,0.f,0.f,0.f}; acc[1] = (f32x4){0.f,0.f,0.f,0.f};
      for (int kt = 0; kt < 4; ++kt) {
        short8 a = *(const short8*)(AB + n16 * 136 + kt * 32 + kb);
        acc[0] = MFMA16(a, w1f[0][kt], acc[0]);
        acc[1] = MFMA16(a, w1f[1][kt], acc[1]);
      }
      __syncthreads();
#pragma unroll
      for (int r = 0; r < 4; ++r) {
        int row = q * 4 + r;
        AB[row * 136 + col0] = f2bf(lrelu(acc[0][r] + b1v0));
        AB[row * 136 + col1] = f2bf(lrelu(acc[1][r] + b1v1));
      }
      __syncthreads();
      acc[0] = (f32x4){0.f,0.f,0.f,0.f}; acc[1] = (f32x4){0.f,0.f,0.f,0.f};
      for (int kt = 0; kt < 4; ++kt) {
        short8 a = *(const short8*)(AB + n16 * 136 + kt * 32 + kb);
        acc[0] = MFMA16(a, w2f[0][kt], acc[0]);
        acc[1] = MFMA16(a, w2f[1][kt], acc[1]);
      }
      if (q < 2) {
#pragma unroll
        for (int r = 0; r < 4; ++r) {
          int j = q * 4 + r;
          msgs[j * 132 + col0] = lrelu(acc[0][r] + b2v0);
          msgs[j * 132 + col1] = lrelu(acc[1][r] + b2v1);
        }
      }
      __syncthreads();
      if (tid < 128) {
        float v = featL[iv * 132 + tid];
        for (int j = 0; j < nvs; ++j) {
          int it = oiL[vslL[j]];
          if (it != iv) v += msgs[j * 132 + tid];
        }
        featL[iv * 132 + tid] = v;
      }
      __syncthreads();
    }
  }

  // ---------------- Phase E: infer_outfit + score ----------------
  if (tid < 128) {
    float sum = 0.0f;
    for (int u = 0; u < nvs; ++u) sum += featL[oiL[vslL[u]] * 132 + tid];
    float v = sum * o2sW[tid];
#pragma unroll
    for (int off = 1; off < 64; off <<= 1) v += __shfl_xor(v, off);
    if (lane == 0) redE[wid] = v;
  }
  __syncthreads();
  if (tid == 0) {
    float t = redE[0] + redE[1] + o2sb[0];
    out[o] = 1.0f / (1.0f + expf(-t));
  }
  __syncthreads();

  // ---------------- Phase F: com_loss ----------------
  {
    const int n = tid >> 4, f = (tid >> 2) & 3, g = tid & 3;
    const float* pa = facL + n * 528 + f * 132;
    const float* pb = facL + n * 528 + g * 132;
    float dot = 0.0f;
    for (int i = 0; i < 32; ++i) {
      float4 a = *(const float4*)(pa + i * 4);
      float4 b = *(const float4*)(pb + i * 4);
      dot += a.x * b.x + a.y * b.y + a.z * b.z + a.w * b.w;
    }
    float v = dot - ((f == g) ? 1.0f : 0.0f);
    float sq = (oiL[n] != -1) ? v * v : 0.0f;
#pragma unroll
    for (int off = 1; off < 64; off <<= 1) sq += __shfl_xor(sq, off);
    if (lane == 0) redE[wid] = sq;
    __syncthreads();
    if (tid == 0) {
      float tot = redE[0] + redE[1] + redE[2] + redE[3];
      atomicAdd(out + 2048, tot * (1.0f / 2048.0f));
    }
  }
}

extern "C" void kernel_launch(void* const* d_in, const int* in_sizes, int n_in,
                              void* d_out, int out_size, void* d_ws, size_t ws_size,
                              hipStream_t stream) {
  float* out = (float*)d_out;
  hipLaunchKernelGGL(zero_com, dim3(1), dim3(64), 0, stream, out);
  hipLaunchKernelGGL(mfgn_kernel, dim3(2048), dim3(256), 0, stream,
                     (const int*)d_in[0],
                     (const float*)d_in[1],
                     (const int*)d_in[2],
                     // d_in[3] items_factors unused (overwritten by creat_factors)
                     (const float*)d_in[4], (const float*)d_in[5],
                     (const float*)d_in[6], (const float*)d_in[7],
                     (const float*)d_in[8], (const float*)d_in[9],
                     (const float*)d_in[10], (const float*)d_in[11],
                     (const float*)d_in[12], (const float*)d_in[13],
                     (const float*)d_in[14], (const float*)d_in[15],
                     (const float*)d_in[16], (const float*)d_in[17],
                     (const float*)d_in[18], (const float*)d_in[19],
                     (const float*)d_in[20], (const float*)d_in[21],
                     out);
}